// Round 7
// baseline (50387.265 us; speedup 1.0000x reference)
//
#include <hip/hip_runtime.h>
#include <hip/hip_fp16.h>
#include <math.h>

// Liquid-network recurrence, hybrid MFMA+dot2. One batch row per CU.
// grid=256, block=256 (4 waves, 1 wave/SIMD -> 512 unified regs/thread).
// K split:
//   k in [0,256):  VALU v_dot2_f32_f16, thread owns cols {2t,2t+1};
//                  80 pairs/col in VGPRs, 48 pairs/col streamed from LDS.
//   k in [256,512): MFMA 16x16x32 f16, M=1; wave w covers cols [128w,128w+128)
//                  as 8 N-tiles x 8 K-tiles; 64 B-frags = 256 u32 in AGPRs
//                  (MFMA reads AGPR natively - no move tax). C row 0 -> recB.
// h: 256 packed f16-pairs in LDS (1 KB, single buffer, 3 barriers/step).

#define HID   512
#define NSTEP 1024
#define BLK   256
#define QV    80                 // register-resident h-pairs per col
#define NSLOT 24                 // LDS weight slots (pairs QV..127, 2 pairs/slot)

// LDS byte offsets
#define OFF_WLS  0               // 24 slots x 256 thr x 16 B = 98304
#define OFF_HB   98304           // 256 u32 = 1024
#define OFF_XLS  99328           // 2048 f32 = 8192
#define OFF_RECB 107520          // 512 f32 = 2048
#define OFF_RED  109568          // 16 f32 = 64
#define OFF_HNA  109632          // 512 f32 = 2048
#define OFF_PSUM 111680          // 160 f32 = 640
#define SMEM_BYTES 112320

typedef _Float16 f16x8 __attribute__((ext_vector_type(8)));
typedef _Float16 half2_t __attribute__((ext_vector_type(2)));
typedef float    f32x4 __attribute__((ext_vector_type(4)));

union FU { f16x8 f; uint4 u; };

__device__ __forceinline__ float dot2f(float acc, uint32_t w, uint32_t h) {
#if __has_builtin(__builtin_amdgcn_fdot2)
    return __builtin_amdgcn_fdot2(__builtin_bit_cast(half2_t, w),
                                  __builtin_bit_cast(half2_t, h), acc, false);
#else
    asm("v_dot2_f32_f16 %0, %1, %2, %0" : "+v"(acc) : "v"(w), "v"(h));
    return acc;
#endif
}

template <int CTRL>
__device__ __forceinline__ float dpp_f(float v) {
    int r = __builtin_amdgcn_update_dpp(0, __builtin_bit_cast(int, v),
                                        CTRL, 0xF, 0xF, true);
    return __builtin_bit_cast(float, r);
}
__device__ __forceinline__ float swz16_f(float v) {
    int r = __builtin_amdgcn_ds_swizzle(__builtin_bit_cast(int, v), 0x401F); // xor16
    return __builtin_bit_cast(float, r);
}
__device__ __forceinline__ uint32_t pack2h(float a, float b) {
    __half2 h2 = __floats2half2_rn(a, b);   // a -> low 16 bits
    union { __half2 h; uint32_t u; } cv; cv.h = h2;
    return cv.u;
}
__device__ __forceinline__ float tanh_fast(float y) {
    float e = __expf(2.0f * y);
    return 1.0f - 2.0f * __builtin_amdgcn_rcpf(e + 1.0f);
}

// B fragment for 16x16x32: elems e=0..7 <-> rows base_row+e, fixed column
__device__ __forceinline__ f16x8 load_bfrag(const float* __restrict__ w,
                                            int base_row, int col) {
    const float* p = w + (size_t)base_row * HID + col;
    f16x8 f;
    #pragma unroll
    for (int e = 0; e < 8; ++e) f[e] = (_Float16)p[e * HID];
    return f;
}

extern "C" __global__ void __launch_bounds__(BLK, 1)
__attribute__((amdgpu_waves_per_eu(1, 1)))
liquid_kernel(const float* __restrict__ x, const float* __restrict__ ctx,
              const float* __restrict__ ce_w1, const float* __restrict__ ce_b1,
              const float* __restrict__ ce_w2, const float* __restrict__ ce_b2,
              const float* __restrict__ in_w, const float* __restrict__ in_b,
              const float* __restrict__ rec_w, const float* __restrict__ tau,
              const float* __restrict__ intra_g, const float* __restrict__ intra_b,
              const float* __restrict__ norm_g, const float* __restrict__ norm_b,
              const float* __restrict__ head_w, const float* __restrict__ head_b,
              float* __restrict__ out)
{
    extern __shared__ char smem[];
    uint4*    wls  = (uint4*)(smem + OFF_WLS);
    uint32_t* hb   = (uint32_t*)(smem + OFF_HB);
    float*    xls  = (float*)(smem + OFF_XLS);
    float*    recB = (float*)(smem + OFF_RECB);
    float*    redS = (float*)(smem + OFF_RED);
    float*    hnA  = (float*)(smem + OFF_HNA);
    float*    psum = (float*)(smem + OFF_PSUM);

    const int b   = blockIdx.x;
    const int t   = threadIdx.x;
    const int l   = t & 63;
    const int w   = t >> 6;        // wave 0..3
    const int lHi = l >> 4;
    const int lLo = l & 15;
    const int cb  = w * 128;       // wave's MFMA column base

    // ---- stage x[b] (8 KB), coalesced ----
    const float* xb = x + (size_t)b * (NSTEP * 2);
    #pragma unroll
    for (int q = 0; q < 8; ++q) xls[t + q * BLK] = xb[t + q * BLK];

    // ---- per-thread params for cols c0=2t, c1=2t+1 ----
    const int c0 = 2 * t, c1 = 2 * t + 1;
    const float g0 = intra_g[c0], g1 = intra_g[c1];
    const float bb0 = intra_b[c0], bb1 = intra_b[c1];
    const float iw00 = in_w[c0], iw01 = in_w[c1];
    const float iw10 = in_w[HID + c0], iw11 = in_w[HID + c1];
    const float ib0 = in_b[c0], ib1 = in_b[c1];
    const float tj0 = tau[c0], tj1 = tau[c1];
    const float it0 = 1.0f / ((tj0 > 30.f) ? tj0 : log1pf(__expf(tj0)));
    const float it1 = 1.0f / ((tj1 > 30.f) ? tj1 : log1pf(__expf(tj1)));

    // ---- h0 = tanh(relu(ctx@ce_w1+b1)@ce_w2+b2) for both cols ----
    float t1[32];
    #pragma unroll
    for (int k = 0; k < 32; ++k) {
        float s = ce_b1[k];
        #pragma unroll
        for (int i = 0; i < 6; ++i) s += ctx[b * 6 + i] * ce_w1[i * 32 + k];
        t1[k] = fmaxf(s, 0.f);
    }
    float s00 = ce_b2[c0], s01 = ce_b2[c1];
    #pragma unroll
    for (int k = 0; k < 32; ++k) {
        s00 += t1[k] * ce_w2[k * HID + c0];
        s01 += t1[k] * ce_w2[k * HID + c1];
    }
    float h0 = tanh_fast(s00);
    float h1 = tanh_fast(s01);

    // ---- dot2 weights, k in [0,2*QV): w0/w1[q] = pack(W[2q,c], W[2q+1,c]) ----
    uint32_t w0[QV], w1[QV];
    #pragma unroll
    for (int q = 0; q < QV; ++q) {
        float2 r0 = *(const float2*)(rec_w + (size_t)(2 * q) * HID + c0);
        float2 r1 = *(const float2*)(rec_w + (size_t)(2 * q + 1) * HID + c0);
        w0[q] = pack2h(r0.x, r1.x);
        w1[q] = pack2h(r0.y, r1.y);
    }
    // ---- LDS weights: pairs QV..127; slot s = (w0[q],w1[q],w0[q+1],w1[q+1]) ----
    #pragma unroll
    for (int s = 0; s < NSLOT; ++s) {
        const int q = QV + 2 * s;
        float2 r0 = *(const float2*)(rec_w + (size_t)(2 * q) * HID + c0);
        float2 r1 = *(const float2*)(rec_w + (size_t)(2 * q + 1) * HID + c0);
        float2 r2 = *(const float2*)(rec_w + (size_t)(2 * q + 2) * HID + c0);
        float2 r3 = *(const float2*)(rec_w + (size_t)(2 * q + 3) * HID + c0);
        uint4 wv;
        wv.x = pack2h(r0.x, r1.x);
        wv.y = pack2h(r0.y, r1.y);
        wv.z = pack2h(r2.x, r3.x);
        wv.w = pack2h(r2.y, r3.y);
        wls[s * BLK + t] = wv;
    }

    // ---- MFMA B fragments (AGPR): k in [256,512), wave cols [cb, cb+128) ----
    f16x8 bB[64];
    #pragma unroll
    for (int kt = 0; kt < 8; ++kt) {
        #pragma unroll
        for (int nt = 0; nt < 8; ++nt)
            bB[kt * 8 + nt] = load_bfrag(rec_w, 256 + kt * 32 + lHi * 8,
                                         cb + nt * 16 + lLo);
    }

    // ---- write h0 pairs ----
    hb[t] = pack2h(h0, h1);
    __syncthreads();

    const uint4* hb4 = (const uint4*)hb;

    for (int step = 0; step < NSTEP; ++step) {
        // ===== MFMA half: k in [256,512) =====
        f32x4 c4[8];
        #pragma unroll
        for (int nt = 0; nt < 8; ++nt) c4[nt] = (f32x4){0.f, 0.f, 0.f, 0.f};
        #pragma unroll
        for (int kt = 0; kt < 8; ++kt) {
            FU au; au.u = hb4[32 + kt * 4 + lHi];
            #pragma unroll
            for (int nt = 0; nt < 8; ++nt)
                c4[nt] = __builtin_amdgcn_mfma_f32_16x16x32_f16(
                             au.f, bB[kt * 8 + nt], c4[nt], 0, 0, 0);
        }

        // ===== dot2 half: k in [0,256) =====
        float a0 = 0.f, a1 = 0.f, a2 = 0.f, a3 = 0.f;
        #pragma unroll
        for (int qq = 0; qq < QV / 4; ++qq) {      // 20 iters, uniform b128 h
            uint4 hv = hb4[qq];
            a0 = dot2f(a0, w0[4 * qq + 0], hv.x);
            a1 = dot2f(a1, w1[4 * qq + 0], hv.x);
            a2 = dot2f(a2, w0[4 * qq + 1], hv.y);
            a3 = dot2f(a3, w1[4 * qq + 1], hv.y);
            a0 = dot2f(a0, w0[4 * qq + 2], hv.z);
            a1 = dot2f(a1, w1[4 * qq + 2], hv.z);
            a2 = dot2f(a2, w0[4 * qq + 3], hv.w);
            a3 = dot2f(a3, w1[4 * qq + 3], hv.w);
        }
        #pragma unroll
        for (int s2 = 0; s2 < NSLOT / 2; ++s2) {   // 12 iters, LDS weights
            const int q = QV + 4 * s2;
            uint4 hv = *(const uint4*)(hb + q);    // uniform, 16B-aligned
            uint4 wA = wls[(2 * s2) * BLK + t];
            uint4 wB = wls[(2 * s2 + 1) * BLK + t];
            a0 = dot2f(a0, wA.x, hv.x);
            a1 = dot2f(a1, wA.y, hv.x);
            a2 = dot2f(a2, wA.z, hv.y);
            a3 = dot2f(a3, wA.w, hv.y);
            a0 = dot2f(a0, wB.x, hv.z);
            a1 = dot2f(a1, wB.y, hv.z);
            a2 = dot2f(a2, wB.z, hv.w);
            a3 = dot2f(a3, wB.w, hv.w);
        }

        // ---- extract MFMA row 0 (lanes 0-15, reg 0) -> recB ----
        if (l < 16) {
            #pragma unroll
            for (int nt = 0; nt < 8; ++nt)
                recB[cb + nt * 16 + lLo] = c4[nt][0];
        }
        __syncthreads();   // (1) recB ready

        // ---- combine + LN ----
        float2 rb = *(const float2*)(recB + c0);
        float2 xv = ((const float2*)xls)[step];
        float v0 = (a0 + a2) + rb.x + fmaf(xv.x, iw00, fmaf(xv.y, iw10, ib0));
        float v1 = (a1 + a3) + rb.y + fmaf(xv.x, iw01, fmaf(xv.y, iw11, ib1));

        float s1 = v0 + v1, sq = v0 * v0 + v1 * v1;
        s1 += dpp_f<0xB1>(s1);  sq += dpp_f<0xB1>(sq);
        s1 += dpp_f<0x4E>(s1);  sq += dpp_f<0x4E>(sq);
        s1 += dpp_f<0x141>(s1); sq += dpp_f<0x141>(sq);
        s1 += dpp_f<0x140>(s1); sq += dpp_f<0x140>(sq);
        s1 += swz16_f(s1);      sq += swz16_f(sq);
        s1 += __shfl_xor(s1, 32); sq += __shfl_xor(sq, 32);
        if (l == 0) { redS[w] = s1; redS[8 + w] = sq; }
        __syncthreads();   // (2) stats ready

        float4 r0 = *(const float4*)redS;
        float4 r1 = *(const float4*)(redS + 8);
        float S1 = (r0.x + r0.y) + (r0.z + r0.w);
        float S2 = (r1.x + r1.y) + (r1.z + r1.w);
        float mu  = S1 * (1.0f / HID);
        float var = S2 * (1.0f / HID) - mu * mu;
        float rs  = rsqrtf(var + 1e-5f);

        float f0 = tanh_fast((v0 - mu) * rs * g0 + bb0);
        float f1 = tanh_fast((v1 - mu) * rs * g1 + bb1);
        h0 = fminf(fmaxf(h0 + (f0 - h0 * it0) * 0.1f, -10.f), 10.f);
        h1 = fminf(fmaxf(h1 + (f1 - h1 * it1) * 0.1f, -10.f), 10.f);
        hb[t] = pack2h(h0, h1);
        __syncthreads();   // (3) h ready
    }

    // ---- final layernorm ----
    float s1 = h0 + h1, sq = h0 * h0 + h1 * h1;
    s1 += dpp_f<0xB1>(s1);  sq += dpp_f<0xB1>(sq);
    s1 += dpp_f<0x4E>(s1);  sq += dpp_f<0x4E>(sq);
    s1 += dpp_f<0x141>(s1); sq += dpp_f<0x141>(sq);
    s1 += dpp_f<0x140>(s1); sq += dpp_f<0x140>(sq);
    s1 += swz16_f(s1);      sq += swz16_f(sq);
    s1 += __shfl_xor(s1, 32); sq += __shfl_xor(sq, 32);
    if (l == 0) { redS[w] = s1; redS[8 + w] = sq; }
    __syncthreads();
    {
        float4 r0 = *(const float4*)redS;
        float4 r1 = *(const float4*)(redS + 8);
        float S1 = (r0.x + r0.y) + (r0.z + r0.w);
        float S2 = (r1.x + r1.y) + (r1.z + r1.w);
        float mu  = S1 * (1.0f / HID);
        float var = S2 * (1.0f / HID) - mu * mu;
        float rs  = rsqrtf(var + 1e-5f);
        hnA[c0] = (h0 - mu) * rs * norm_g[c0] + norm_b[c0];
        hnA[c1] = (h1 - mu) * rs * norm_g[c1] + norm_b[c1];
    }
    __syncthreads();

    // ---- heads: out[b, a] = hn . head_w[:, a] + head_b[a] ----
    if (t < 160) {
        int a = t >> 3, part = t & 7;
        float s = 0.f;
        #pragma unroll 8
        for (int q = 0; q < 64; ++q) {
            int row = part * 64 + q;
            s += hnA[row] * head_w[row * 20 + a];
        }
        psum[a * 8 + part] = s;
    }
    __syncthreads();
    if (t < 20) {
        float s = head_b[t];
        #pragma unroll
        for (int q = 0; q < 8; ++q) s += psum[t * 8 + q];
        out[b * 20 + t] = s;
    }
}

extern "C" void kernel_launch(void* const* d_in, const int* in_sizes, int n_in,
                              void* d_out, int out_size, void* d_ws, size_t ws_size,
                              hipStream_t stream) {
    const float* x       = (const float*)d_in[0];
    const float* ctx     = (const float*)d_in[1];
    const float* ce_w1   = (const float*)d_in[2];
    const float* ce_b1   = (const float*)d_in[3];
    const float* ce_w2   = (const float*)d_in[4];
    const float* ce_b2   = (const float*)d_in[5];
    const float* in_w    = (const float*)d_in[6];
    const float* in_b    = (const float*)d_in[7];
    const float* rec_w   = (const float*)d_in[8];
    const float* tau     = (const float*)d_in[9];
    const float* intra_g = (const float*)d_in[10];
    const float* intra_b = (const float*)d_in[11];
    const float* norm_g  = (const float*)d_in[12];
    const float* norm_b  = (const float*)d_in[13];
    const float* head_w  = (const float*)d_in[14];
    const float* head_b  = (const float*)d_in[15];
    float* outp = (float*)d_out;

    (void)d_ws; (void)ws_size; (void)n_in; (void)in_sizes; (void)out_size;

    // opt-in to >64KB dynamic LDS (160 KB/CU on gfx950); host-side, capture-safe
    hipFuncSetAttribute((const void*)liquid_kernel,
                        hipFuncAttributeMaxDynamicSharedMemorySize, SMEM_BYTES);

    liquid_kernel<<<dim3(256), dim3(BLK), SMEM_BYTES, stream>>>(
        x, ctx, ce_w1, ce_b1, ce_w2, ce_b2, in_w, in_b, rec_w, tau,
        intra_g, intra_b, norm_g, norm_b, head_w, head_b, outp);
}

// Round 8
// 1999.947 us; speedup vs baseline: 25.1943x; 25.1943x over previous
//
#include <hip/hip_runtime.h>
#include <hip/hip_fp16.h>
#include <math.h>

// Liquid-network recurrence, split-K pk_fma. One batch row per CU.
// grid=256, block=512 (8 waves, 2 waves/SIMD -> 256 unified regs/thread).
// Thread t = 8g+p: computes cols [8g,8g+8) over k-slice [64p,64p+64)
// with v_pk_fma_f16 (f16x2 accumulate, full-rate), then the validated
// 3-round DPP mirror transpose-reduce lands rec[t] on thread t.
// Weights: 32 k2-pairs x 8 cols = 256 u32/thread:
//   k2 0..22  -> VGPR (184 u32; sized to fit the 256-reg budget arch-only)
//   k2 23..31 -> LDS (18 uint4/thread/step, 147 KB)
// h: f16, single buffer, per-slice rotation swizzle (conflict-free reads),
// all LDS addresses precomputed step-invariant. 2 barriers/step.

#define HID    512
#define NSTEP  1024
#define BLK    512
#define KREG   23

// LDS byte offsets
#define OFF_WLS  0               // 18 slots x 512 x 16 B = 147456
#define OFF_HB   147456          // 256 u32 = 1024
#define OFF_XLS  148480          // 2048 f32 = 8192
#define OFF_RED  156672          // 16 f32 = 64
#define OFF_HNA  156736          // 512 f32 = 2048
#define OFF_PSUM 158784          // 160 f32 = 640
#define SMEM_BYTES 159424

template <int CTRL>
__device__ __forceinline__ float dpp_f(float v) {
    int r = __builtin_amdgcn_update_dpp(0, __builtin_bit_cast(int, v),
                                        CTRL, 0xF, 0xF, true);
    return __builtin_bit_cast(float, r);
}
// 0xB1 quad_perm xor1, 0x4E quad_perm xor2, 0x1B quad mirror,
// 0x141 row_half_mirror, 0x140 row_mirror.

__device__ __forceinline__ float swz16_f(float v) {
    int r = __builtin_amdgcn_ds_swizzle(__builtin_bit_cast(int, v), 0x401F); // xor16
    return __builtin_bit_cast(float, r);
}
__device__ __forceinline__ uint32_t pack2h(float a, float b) {
    __half2 h2 = __floats2half2_rn(a, b);   // a -> low 16 bits
    union { __half2 h; uint32_t u; } cv; cv.h = h2;
    return cv.u;
}
__device__ __forceinline__ __half2 u2h(uint32_t u) {
    union { uint32_t u; __half2 h; } cv; cv.u = u;
    return cv.h;
}
__device__ __forceinline__ float tanh_fast(float y) {
    float e = __expf(2.0f * y);
    return 1.0f - 2.0f * __builtin_amdgcn_rcpf(e + 1.0f);
}

extern "C" __global__ void __launch_bounds__(BLK, 2)
__attribute__((amdgpu_waves_per_eu(2, 2)))
liquid_kernel(const float* __restrict__ x, const float* __restrict__ ctx,
              const float* __restrict__ ce_w1, const float* __restrict__ ce_b1,
              const float* __restrict__ ce_w2, const float* __restrict__ ce_b2,
              const float* __restrict__ in_w, const float* __restrict__ in_b,
              const float* __restrict__ rec_w, const float* __restrict__ tau,
              const float* __restrict__ intra_g, const float* __restrict__ intra_b,
              const float* __restrict__ norm_g, const float* __restrict__ norm_b,
              const float* __restrict__ head_w, const float* __restrict__ head_b,
              float* __restrict__ out)
{
    extern __shared__ char smem[];
    uint4*  wls4 = (uint4*)(smem + OFF_WLS);
    float*  xls  = (float*)(smem + OFF_XLS);
    float*  redS = (float*)(smem + OFF_RED);
    float*  hnA  = (float*)(smem + OFF_HNA);
    float*  psum = (float*)(smem + OFF_PSUM);
    char*   hbB  = smem + OFF_HB;
    __half* hbH  = (__half*)hbB;

    const int b  = blockIdx.x;
    const int t  = threadIdx.x;
    const int p  = t & 7;          // k-slice 0..7 (lane bits 0..2)
    const int g  = t >> 3;         // col group 0..63
    const int wv = t >> 6;         // wave id 0..7
    const int ln = t & 63;

    // ---- stage x[b] (8 KB), coalesced ----
    const float* xb = x + (size_t)b * (NSTEP * 2);
    #pragma unroll
    for (int q = 0; q < 4; ++q) xls[t + q * BLK] = xb[t + q * BLK];

    // ---- per-thread params (col t) ----
    const float g_j  = intra_g[t];
    const float bb_j = intra_b[t];
    const float iw0  = in_w[t];
    const float iw1  = in_w[HID + t];
    const float ib_j = in_b[t];
    const float tj   = tau[t];
    const float sp   = (tj > 30.f) ? tj : log1pf(__expf(tj));
    const float itau = 1.0f / sp;

    // ---- h0 = tanh(relu(ctx@ce_w1+b1)@ce_w2+b2) for col t ----
    float t1[32];
    #pragma unroll
    for (int k = 0; k < 32; ++k) {
        float s = ce_b1[k];
        #pragma unroll
        for (int i = 0; i < 6; ++i) s += ctx[b * 6 + i] * ce_w1[i * 32 + k];
        t1[k] = fmaxf(s, 0.f);
    }
    float s0 = ce_b2[t];
    #pragma unroll
    for (int k = 0; k < 32; ++k) s0 += t1[k] * ce_w2[k * HID + t];
    float h = tanh_fast(s0);

    // ---- weights: pair k2 = rows (64p+2k2, +1), cols 8g..8g+7 ----
    uint32_t wreg[KREG * 8];
    #pragma unroll
    for (int k2 = 0; k2 < KREG; ++k2) {
        const float* pa = rec_w + (size_t)(64 * p + 2 * k2) * HID + 8 * g;
        float4 a0 = *(const float4*)(pa);
        float4 a1 = *(const float4*)(pa + 4);
        float4 b0 = *(const float4*)(pa + HID);
        float4 b1 = *(const float4*)(pa + HID + 4);
        wreg[k2 * 8 + 0] = pack2h(a0.x, b0.x);
        wreg[k2 * 8 + 1] = pack2h(a0.y, b0.y);
        wreg[k2 * 8 + 2] = pack2h(a0.z, b0.z);
        wreg[k2 * 8 + 3] = pack2h(a0.w, b0.w);
        wreg[k2 * 8 + 4] = pack2h(a1.x, b1.x);
        wreg[k2 * 8 + 5] = pack2h(a1.y, b1.y);
        wreg[k2 * 8 + 6] = pack2h(a1.z, b1.z);
        wreg[k2 * 8 + 7] = pack2h(a1.w, b1.w);
    }
    #pragma unroll
    for (int m = 0; m < 32 - KREG; ++m) {
        const int k2 = KREG + m;
        const float* pa = rec_w + (size_t)(64 * p + 2 * k2) * HID + 8 * g;
        float4 a0 = *(const float4*)(pa);
        float4 a1 = *(const float4*)(pa + 4);
        float4 b0 = *(const float4*)(pa + HID);
        float4 b1 = *(const float4*)(pa + HID + 4);
        uint4 wA, wB;
        wA.x = pack2h(a0.x, b0.x); wA.y = pack2h(a0.y, b0.y);
        wA.z = pack2h(a0.z, b0.z); wA.w = pack2h(a0.w, b0.w);
        wB.x = pack2h(a1.x, b1.x); wB.y = pack2h(a1.y, b1.y);
        wB.z = pack2h(a1.z, b1.z); wB.w = pack2h(a1.w, b1.w);
        wls4[(2 * m + 0) * BLK + t] = wA;
        wls4[(2 * m + 1) * BLK + t] = wB;
    }

    // ---- h swizzle (per-slice rotation): logical u32 i=32s+4q+e stored at
    //      j = 32s + 4*((q+s)&7) + e.  Step-invariant write index (col t): ----
    int hwIdx;
    {
        const int sW = t >> 6, qW = (t >> 3) & 7, eW = (t >> 1) & 3;
        const int jW = 32 * sW + 4 * ((qW + sW) & 7) + eW;
        hwIdx = 2 * jW + (t & 1);
    }
    // Step-invariant read addresses: read #r -> logical quad r of slice p.
    int hAddr[8];
    #pragma unroll
    for (int r = 0; r < 8; ++r) hAddr[r] = 128 * p + 16 * ((r + p) & 7);

    hbH[hwIdx] = __float2half_rn(h);
    __syncthreads();

    for (int step = 0; step < NSTEP; ++step) {
        // ---- pk_fma matvec partials: 8 cols over k-slice [64p,64p+64) ----
        const __half2 z2 = __floats2half2_rn(0.f, 0.f);
        __half2 acc2[8] = {z2, z2, z2, z2, z2, z2, z2, z2};
        #pragma unroll
        for (int q = 0; q < 8; ++q) {
            uint4 hq = *(const uint4*)(hbB + hAddr[q]);   // logical quad q
            #pragma unroll
            for (int e = 0; e < 4; ++e) {
                const int k2 = 4 * q + e;
                const uint32_t hp = (e == 0) ? hq.x : (e == 1) ? hq.y
                                  : (e == 2) ? hq.z : hq.w;
                const __half2 h2 = u2h(hp);
                if (k2 < KREG) {
                    #pragma unroll
                    for (int c = 0; c < 8; ++c)
                        acc2[c] = __hfma2(u2h(wreg[k2 * 8 + c]), h2, acc2[c]);
                } else {
                    const int m = k2 - KREG;
                    uint4 wA = wls4[(2 * m + 0) * BLK + t];
                    uint4 wB = wls4[(2 * m + 1) * BLK + t];
                    acc2[0] = __hfma2(u2h(wA.x), h2, acc2[0]);
                    acc2[1] = __hfma2(u2h(wA.y), h2, acc2[1]);
                    acc2[2] = __hfma2(u2h(wA.z), h2, acc2[2]);
                    acc2[3] = __hfma2(u2h(wA.w), h2, acc2[3]);
                    acc2[4] = __hfma2(u2h(wB.x), h2, acc2[4]);
                    acc2[5] = __hfma2(u2h(wB.y), h2, acc2[5]);
                    acc2[6] = __hfma2(u2h(wB.z), h2, acc2[6]);
                    acc2[7] = __hfma2(u2h(wB.w), h2, acc2[7]);
                }
            }
        }
        float fc[8];
        #pragma unroll
        for (int c = 0; c < 8; ++c)
            fc[c] = __low2float(acc2[c]) + __high2float(acc2[c]);

        // ---- DPP mirror transpose-reduce (validated round 5): rec[t] ----
        float b4[4];
        {
            const bool hi = (p & 4);
            #pragma unroll
            for (int i = 0; i < 4; ++i) {
                float keep = hi ? fc[i + 4] : fc[i];
                float send = hi ? fc[i]     : fc[i + 4];
                b4[i] = keep + dpp_f<0x141>(send);
            }
        }
        float c2[2];
        {
            const bool hi = (p & 2);
            #pragma unroll
            for (int i = 0; i < 2; ++i) {
                float keep = hi ? b4[i + 2] : b4[i];
                float send = hi ? b4[i]     : b4[i + 2];
                c2[i] = keep + dpp_f<0x1B>(send);
            }
        }
        float rec;
        {
            const bool hi = (p & 1);
            float keep = hi ? c2[1] : c2[0];
            float send = hi ? c2[0] : c2[1];
            rec = keep + dpp_f<0xB1>(send);
        }

        float2 xv = ((const float2*)xls)[step];
        float v = fmaf(xv.x, iw0, fmaf(xv.y, iw1, ib_j + rec));

        // ---- LN reduce (validated): 4 DPP + xor16 + xor32 ----
        float s1 = v, sq = v * v;
        s1 += dpp_f<0xB1>(s1);  sq += dpp_f<0xB1>(sq);
        s1 += dpp_f<0x4E>(s1);  sq += dpp_f<0x4E>(sq);
        s1 += dpp_f<0x141>(s1); sq += dpp_f<0x141>(sq);
        s1 += dpp_f<0x140>(s1); sq += dpp_f<0x140>(sq);
        s1 += swz16_f(s1);      sq += swz16_f(sq);
        s1 += __shfl_xor(s1, 32); sq += __shfl_xor(sq, 32);
        if (ln == 0) { redS[wv] = s1; redS[8 + wv] = sq; }
        __syncthreads();   // (1) stats ready; also fences h reads

        const float4* rp = (const float4*)redS;
        float4 r0 = rp[0], r1 = rp[1], r2 = rp[2], r3 = rp[3];
        float S1 = ((r0.x + r0.y) + (r0.z + r0.w)) + ((r1.x + r1.y) + (r1.z + r1.w));
        float S2 = ((r2.x + r2.y) + (r2.z + r2.w)) + ((r3.x + r3.y) + (r3.z + r3.w));
        float mu  = S1 * (1.0f / HID);
        float var = S2 * (1.0f / HID) - mu * mu;
        float rs  = rsqrtf(var + 1e-5f);
        float f   = tanh_fast((v - mu) * rs * g_j + bb_j);

        h = h + (f - h * itau) * 0.1f;
        h = fminf(fmaxf(h, -10.f), 10.f);
        hbH[hwIdx] = __float2half_rn(h);
        __syncthreads();   // (2) h ready
    }

    // ---- final layernorm ----
    float s1 = h, sq = h * h;
    s1 += dpp_f<0xB1>(s1);  sq += dpp_f<0xB1>(sq);
    s1 += dpp_f<0x4E>(s1);  sq += dpp_f<0x4E>(sq);
    s1 += dpp_f<0x141>(s1); sq += dpp_f<0x141>(sq);
    s1 += dpp_f<0x140>(s1); sq += dpp_f<0x140>(sq);
    s1 += swz16_f(s1);      sq += swz16_f(sq);
    s1 += __shfl_xor(s1, 32); sq += __shfl_xor(sq, 32);
    if (ln == 0) { redS[wv] = s1; redS[8 + wv] = sq; }
    __syncthreads();
    {
        const float4* rp = (const float4*)redS;
        float4 r0 = rp[0], r1 = rp[1], r2 = rp[2], r3 = rp[3];
        float S1 = ((r0.x + r0.y) + (r0.z + r0.w)) + ((r1.x + r1.y) + (r1.z + r1.w));
        float S2 = ((r2.x + r2.y) + (r2.z + r2.w)) + ((r3.x + r3.y) + (r3.z + r3.w));
        float mu  = S1 * (1.0f / HID);
        float var = S2 * (1.0f / HID) - mu * mu;
        float rs  = rsqrtf(var + 1e-5f);
        hnA[t] = (h - mu) * rs * norm_g[t] + norm_b[t];
    }
    __syncthreads();

    // ---- heads: out[b, a] = hn . head_w[:, a] + head_b[a] ----
    if (t < 160) {
        int a = t >> 3, part = t & 7;
        float s = 0.f;
        #pragma unroll 8
        for (int q = 0; q < 64; ++q) {
            int row = part * 64 + q;
            s += hnA[row] * head_w[row * 20 + a];
        }
        psum[a * 8 + part] = s;
    }
    __syncthreads();
    if (t < 20) {
        float s = head_b[t];
        #pragma unroll
        for (int q = 0; q < 8; ++q) s += psum[t * 8 + q];
        out[b * 20 + t] = s;
    }
}

extern "C" void kernel_launch(void* const* d_in, const int* in_sizes, int n_in,
                              void* d_out, int out_size, void* d_ws, size_t ws_size,
                              hipStream_t stream) {
    const float* x       = (const float*)d_in[0];
    const float* ctx     = (const float*)d_in[1];
    const float* ce_w1   = (const float*)d_in[2];
    const float* ce_b1   = (const float*)d_in[3];
    const float* ce_w2   = (const float*)d_in[4];
    const float* ce_b2   = (const float*)d_in[5];
    const float* in_w    = (const float*)d_in[6];
    const float* in_b    = (const float*)d_in[7];
    const float* rec_w   = (const float*)d_in[8];
    const float* tau     = (const float*)d_in[9];
    const float* intra_g = (const float*)d_in[10];
    const float* intra_b = (const float*)d_in[11];
    const float* norm_g  = (const float*)d_in[12];
    const float* norm_b  = (const float*)d_in[13];
    const float* head_w  = (const float*)d_in[14];
    const float* head_b  = (const float*)d_in[15];
    float* outp = (float*)d_out;

    (void)d_ws; (void)ws_size; (void)n_in; (void)in_sizes; (void)out_size;

    // opt-in to >64KB dynamic LDS (160 KB/CU on gfx950); host-side, capture-safe
    hipFuncSetAttribute((const void*)liquid_kernel,
                        hipFuncAttributeMaxDynamicSharedMemorySize, SMEM_BYTES);

    liquid_kernel<<<dim3(256), dim3(BLK), SMEM_BYTES, stream>>>(
        x, ctx, ce_w1, ce_b1, ce_w2, ce_b2, in_w, in_b, rec_w, tau,
        intra_g, intra_b, norm_g, norm_b, head_w, head_b, outp);
}